// Round 10
// baseline (3799.021 us; speedup 1.0000x reference)
//
#include <hip/hip_runtime.h>
#include <hip/hip_bf16.h>

#define BB 64
#define EE 512
#define HH 1024
#define KK 1536
#define VV 50257
#define SS 512

#define NWG1 64    // G1 blocks: mi=bid&3 (16 rows), ni=bid>>2 (16 x 64-col tiles)
#define NWG2 32    // G2 blocks: mi=rb&3,  ni=rb>>2 (8 x 64-col tiles)
#define NWG (NWG1 + NWG2)
#define PADU 32    // unsigned per flag slot = 128 B line
#define GUARD_MAX 8192

typedef __bf16 bf16x8 __attribute__((ext_vector_type(8)));
typedef float f32x4 __attribute__((ext_vector_type(4)));
typedef unsigned u32x2 __attribute__((ext_vector_type(2)));
typedef unsigned long long u64;

union frg { unsigned u[4]; bf16x8 h; };
union pk2 { __bf16 h[2]; unsigned u; };

__device__ __forceinline__ bf16x8 load_bf8(const __bf16* p) {
    return *reinterpret_cast<const bf16x8*>(p);
}

__device__ __forceinline__ bf16x8 cvt8(const float* p) {
    f32x4 a = *reinterpret_cast<const f32x4*>(p);
    f32x4 b = *reinterpret_cast<const f32x4*>(p + 4);
    bf16x8 r;
    r[0] = (__bf16)a[0]; r[1] = (__bf16)a[1]; r[2] = (__bf16)a[2]; r[3] = (__bf16)a[3];
    r[4] = (__bf16)b[0]; r[5] = (__bf16)b[1]; r[6] = (__bf16)b[2]; r[7] = (__bf16)b[3];
    return r;
}

// 8B tagged-message ops: naturally-aligned dwordx2 is single-copy atomic
// (same primitive as rounds 4-6's __hip_atomic 8B ops, proven on this HW).
// sc0 sc1 -> device coherence point (round-7/8-proven routing).
template<int OFF>
__device__ __forceinline__ u32x2 ld8o(const void* p) {
    u32x2 r;
    asm volatile("global_load_dwordx2 %0, %1, off offset:%2 sc0 sc1"
                 : "=v"(r) : "v"(p), "i"(OFF));
    return r;
}
template<int OFF>
__device__ __forceinline__ void st8o(void* p, u32x2 v) {
    asm volatile("global_store_dwordx2 %0, %1, off offset:%2 sc0 sc1"
                 :: "v"(p), "v"(v), "i"(OFF));
}

// Wave-parallel min over nslots flag slots (broadcast to all lanes).
__device__ __forceinline__ unsigned minpoll(const unsigned* slots, int nslots) {
    const int l = threadIdx.x & 63;
    unsigned v = 0xFFFFFFFFu;
    if (l < nslots)
        v = __hip_atomic_load(&slots[l * PADU], __ATOMIC_RELAXED,
                              __HIP_MEMORY_SCOPE_AGENT);
    #pragma unroll
    for (int o = 32; o; o >>= 1) {
        unsigned u = (unsigned)__shfl_xor((int)v, o, 64);
        v = u < v ? u : v;
    }
    return v;
}

// Fast tanh via v_exp; rel err ~1e-6 << bf16 storage quantization.
__device__ __forceinline__ float ftanh(float x) {
    float ax = fabsf(x);
    float e = __expf(-2.0f * ax);
    float r = (1.0f - e) / (1.0f + e);
    return x < 0.0f ? -r : r;
}

// Decode tokens to int32 (auto-detect int64 vs int32) + zero the f2 flags.
__global__ void tokens_kernel(const void* __restrict__ seq, int* __restrict__ tok,
                              unsigned* __restrict__ bar) {
    int z = blockIdx.x * 256 + threadIdx.x;
    if (z < 4 * 32 * PADU)
        __hip_atomic_store(&bar[z], 0u, __ATOMIC_RELAXED, __HIP_MEMORY_SCOPE_AGENT);
    const unsigned* u = (const unsigned*)seq;
    bool is64 = true;
    #pragma unroll 1
    for (int i = 0; i < 64; ++i) {
        if (u[2 * i + 1] != 0u) { is64 = false; break; }
    }
    int i = blockIdx.x * 256 + threadIdx.x;
    if (i < BB * SS) tok[i] = is64 ? (int)u[2 * i] : (int)u[i];
}

// fp32 [R][C] row-major -> bf16 [C][R]
__global__ __launch_bounds__(256) void transpose_kernel(
    const float* __restrict__ in, __bf16* __restrict__ out, int R, int C) {
    __shared__ float t[32][33];
    int bc = C >> 5;
    int br = blockIdx.x / bc;
    int bco = blockIdx.x % bc;
    int R0 = br << 5, C0 = bco << 5;
    int c = threadIdx.x & 31, r0 = threadIdx.x >> 5;
    #pragma unroll
    for (int i = 0; i < 4; ++i) {
        int r = r0 + i * 8;
        t[r][c] = in[(size_t)(R0 + r) * C + C0 + c];
    }
    __syncthreads();
    #pragma unroll
    for (int i = 0; i < 4; ++i) {
        int r = r0 + i * 8;
        out[(size_t)(C0 + r) * R + R0 + c] = (__bf16)t[c][r];
    }
}

// Zero message slots 1..7 each launch (kills stale tags across graph replays).
__global__ void msgclear_kernel(u64* __restrict__ h1m, u64* __restrict__ h2m) {
    size_t z = (size_t)blockIdx.x * 256 + threadIdx.x;
    if (z < (size_t)7 * 64 * 512) h1m[(size_t)64 * 512 + z] = 0ull;
    else {
        z -= (size_t)7 * 64 * 512;
        if (z < (size_t)7 * 64 * 256) h2m[(size_t)64 * 256 + z] = 0ull;
    }
}

// Init slot 0 messages (tag 0) + raw slot-0 buffers for the fallback path.
__global__ void init_kernel(const float* __restrict__ h1, const float* __restrict__ h2,
                            u64* __restrict__ h1m, u64* __restrict__ h2m,
                            __bf16* __restrict__ h1p0, __bf16* __restrict__ h2p0) {
    int i = blockIdx.x * 256 + threadIdx.x;
    if (i < 64 * 512) {
        int row = i >> 9, m = i & 511;
        pk2 p;
        p.h[0] = (__bf16)h1[row * HH + 2 * m];
        p.h[1] = (__bf16)h1[row * HH + 2 * m + 1];
        h1m[i] = (u64)p.u;                 // tag 0 in high dword
        h1p0[row * HH + 2 * m] = p.h[0];
        h1p0[row * HH + 2 * m + 1] = p.h[1];
    } else {
        int j = i - 64 * 512;
        if (j < 64 * 256) {
            int row = j >> 8, m = j & 255;
            pk2 p;
            p.h[0] = (__bf16)h2[row * EE + 2 * m];
            p.h[1] = (__bf16)h2[row * EE + 2 * m + 1];
            h2m[j] = (u64)p.u;
            h2p0[row * EE + 2 * m] = p.h[0];
            h2p0[row * EE + 2 * m + 1] = p.h[1];
        }
    }
}

// Persistent decoupled chains with TAGGED-MESSAGE exchange.
// h1m[slot][row][512 msgs], h2m[slot][row][256 msgs]; msg = {2 bf16, tag}.
// G1@i: emb MFMAs -> WAR check (f2min>=i-7, cached) -> poll h1_i msgs (tag==i,
//   the loads ARE the operands) -> 32 MFMA -> LDS reduce -> tanh -> store
//   h1_{i+1} msgs (tag i+1). No flags, no drains on the critical path.
// G2@j: poll h1_j (tag j) + h2_{j-1} (tag j-1) in one batch -> post f2=j ->
//   48 MFMA -> reduce -> store h2_j msgs (tag j).
// Lockstep: a block at step t consumed ALL peers' step-t messages -> peers
// finished t-1 -> skew <=1 -> depth-8 ring safe (G2 trailing covered by f2).
__global__ __launch_bounds__(256, 1) void rnn_persist5(
    const int* __restrict__ tok32, const float* __restrict__ embW,
    const float* __restrict__ b1, const float* __restrict__ b2,
    const __bf16* __restrict__ W1t, const __bf16* __restrict__ W2t,
    u64* __restrict__ h1m, u64* __restrict__ h2m,
    float* __restrict__ h1out, float* __restrict__ h2out,
    unsigned* __restrict__ bar) {
    const int bid = blockIdx.x;
    const bool g1 = bid < NWG1;
    const int rb = g1 ? bid : bid - NWG1;
    const int mi = rb & 3;
    const int ni = rb >> 2;
    const int m0 = mi << 4;
    const int n0 = ni << 6;
    const int tid = threadIdx.x;
    const int w = tid >> 6;
    const int l = tid & 63;
    const int l16 = l & 15;
    const int kg = l >> 4;
    unsigned* f2s = bar + mi * (32 * PADU);
    unsigned* myf2 = &f2s[(ni * 4 + w) * PADU];

    __shared__ int tok_s[SS][16];
    __shared__ float red[2][4][16][68];

    if (g1) {
        for (int idx = tid; idx < SS * 16; idx += 256) {
            int t = idx >> 4, r = idx & 15;
            tok_s[t][r] = tok32[(m0 + r) * SS + t];
        }
    }

    // Register-resident weights: wave w holds K-slices {w+4t, t=0..11}.
    const __bf16* Wt = g1 ? W1t : W2t;
    bf16x8 wreg[12][4];
    #pragma unroll
    for (int t = 0; t < 12; ++t) {
        const int kb = 32 * (w + 4 * t) + kg * 8;
        #pragma unroll
        for (int nf = 0; nf < 4; ++nf)
            wreg[t][nf] = load_bf8(Wt + (size_t)(n0 + nf * 16 + l16) * KK + kb);
    }
    {   // Pin in the register file (round-3 lesson).
        f32x4* p1 = reinterpret_cast<f32x4*>(&wreg[0][0]);
        #pragma unroll
        for (int q = 0; q < 48; ++q) asm volatile("" : "+v"(p1[q]));
    }

    // Epilogue mapping (lanes<32): row = 4w + (l>>3), cols c1 = (l&7)*8.
    const int r1 = 4 * w + ((l & 31) >> 3);
    const int c1 = (l & 7) * 8;
    const float* bias = g1 ? b1 : b2;
    const f32x4 blo = *reinterpret_cast<const f32x4*>(bias + n0 + c1);
    const f32x4 bhi = *reinterpret_cast<const f32x4*>(bias + n0 + c1 + 4);
    const int laneoff = 16 * w + 4 * kg;    // msg offset of this lane's K-slices

    __syncthreads();

    if (g1) {
        unsigned f2c = 0;
        for (int i = 0; i < SS; ++i) {
            const int si = i & 7, sn = (i + 1) & 7;

            // Pre-poll: embedding-part MFMAs (cached path).
            f32x4 acc[4] = {{0,0,0,0},{0,0,0,0},{0,0,0,0},{0,0,0,0}};
            const float* er = embW + (size_t)tok_s[i][l16] * EE;
            #pragma unroll
            for (int t = 0; t < 4; ++t) {
                bf16x8 ae = cvt8(er + 32 * (w + 4 * t) + kg * 8);
                #pragma unroll
                for (int nf = 0; nf < 4; ++nf)
                    acc[nf] = __builtin_amdgcn_mfma_f32_16x16x32_bf16(
                        ae, wreg[t][nf], acc[nf], 0, 0, 0);
            }
            __builtin_amdgcn_sched_barrier(0);

            // Amortized ring-WAR: slot sn holds h1_{i-7}; G2 must be done.
            if (i >= 7 && (int)f2c < i - 7) {
                int g = 0;
                do { f2c = minpoll(f2s, 32); } while ((int)f2c < i - 7 && ++g < GUARD_MAX);
            }

            // Poll h1_i: 32 tagged 8B loads/lane; on success operands are live.
            const char* pb = (const char*)(h1m +
                ((size_t)(si * 64 + m0 + l16) * 512 + laneoff));
            u32x2 mm[8][4];
            int guard = 0;
            for (;;) {
                #define LDU(u) \
                    mm[u][0] = ld8o<(u)*512 +  0>(pb); \
                    mm[u][1] = ld8o<(u)*512 +  8>(pb); \
                    mm[u][2] = ld8o<(u)*512 + 16>(pb); \
                    mm[u][3] = ld8o<(u)*512 + 24>(pb);
                LDU(0) LDU(1) LDU(2) LDU(3) LDU(4) LDU(5) LDU(6) LDU(7)
                #undef LDU
                asm volatile("s_waitcnt vmcnt(0)" ::: "memory");
                __builtin_amdgcn_sched_barrier(0);
                bool ok = true;
                #pragma unroll
                for (int u = 0; u < 8; ++u)
                    #pragma unroll
                    for (int q = 0; q < 4; ++q) ok &= (mm[u][q][1] == (unsigned)i);
                if (__all(ok)) break;
                if (++guard > GUARD_MAX) break;
            }

            #pragma unroll
            for (int u = 0; u < 8; ++u) {
                frg f;
                f.u[0] = mm[u][0][0]; f.u[1] = mm[u][1][0];
                f.u[2] = mm[u][2][0]; f.u[3] = mm[u][3][0];
                #pragma unroll
                for (int nf = 0; nf < 4; ++nf)
                    acc[nf] = __builtin_amdgcn_mfma_f32_16x16x32_bf16(
                        f.h, wreg[u + 4][nf], acc[nf], 0, 0, 0);
            }

            // D layout: col = lane&15, row = (lane>>4)*4 + reg.
            #pragma unroll
            for (int nf = 0; nf < 4; ++nf)
                #pragma unroll
                for (int q = 0; q < 4; ++q)
                    red[i & 1][w][kg * 4 + q][nf * 16 + l16] = acc[nf][q];
            __syncthreads();

            if ((l & 63) < 32) {
                f32x4 lo = blo, hi = bhi;
                #pragma unroll
                for (int p = 0; p < 4; ++p) {
                    lo += *reinterpret_cast<const f32x4*>(&red[i & 1][p][r1][c1]);
                    hi += *reinterpret_cast<const f32x4*>(&red[i & 1][p][r1][c1 + 4]);
                }
                float s[8];
                #pragma unroll
                for (int j = 0; j < 4; ++j) { s[j] = ftanh(lo[j]); s[j + 4] = ftanh(hi[j]); }
                char* dp = (char*)(h1m +
                    ((size_t)(sn * 64 + m0 + r1) * 512 + (n0 + c1) / 2));
                const unsigned tg = (unsigned)(i + 1);
                #define STU(q, OFF) { pk2 p; p.h[0]=(__bf16)s[2*(q)]; p.h[1]=(__bf16)s[2*(q)+1]; \
                                      u32x2 v; v[0]=p.u; v[1]=tg; st8o<OFF>(dp, v); }
                STU(0, 0) STU(1, 8) STU(2, 16) STU(3, 24)
                #undef STU
                if (i == SS - 1) {
                    float* op = h1out + (m0 + r1) * HH + n0 + c1;
                    #pragma unroll
                    for (int j = 0; j < 8; ++j) op[j] = s[j];
                }
            }
        }
    } else {
        for (int j = 1; j <= SS; ++j) {
            const int sj = j & 7, sp = (j - 1) & 7;
            const char* pb1 = (const char*)(h1m +
                ((size_t)(sj * 64 + m0 + l16) * 512 + laneoff));
            const char* pb2 = (const char*)(h2m +
                ((size_t)(sp * 64 + m0 + l16) * 256 + laneoff));
            u32x2 ma[8][4], mb[4][4];
            int guard = 0;
            for (;;) {
                #define LDA(u) \
                    ma[u][0] = ld8o<(u)*512 +  0>(pb1); \
                    ma[u][1] = ld8o<(u)*512 +  8>(pb1); \
                    ma[u][2] = ld8o<(u)*512 + 16>(pb1); \
                    ma[u][3] = ld8o<(u)*512 + 24>(pb1);
                #define LDB(u) \
                    mb[u][0] = ld8o<(u)*512 +  0>(pb2); \
                    mb[u][1] = ld8o<(u)*512 +  8>(pb2); \
                    mb[u][2] = ld8o<(u)*512 + 16>(pb2); \
                    mb[u][3] = ld8o<(u)*512 + 24>(pb2);
                LDA(0) LDA(1) LDA(2) LDA(3) LDA(4) LDA(5) LDA(6) LDA(7)
                LDB(0) LDB(1) LDB(2) LDB(3)
                #undef LDA
                #undef LDB
                asm volatile("s_waitcnt vmcnt(0)" ::: "memory");
                __builtin_amdgcn_sched_barrier(0);
                bool ok = true;
                #pragma unroll
                for (int u = 0; u < 8; ++u)
                    #pragma unroll
                    for (int q = 0; q < 4; ++q) ok &= (ma[u][q][1] == (unsigned)j);
                #pragma unroll
                for (int u = 0; u < 4; ++u)
                    #pragma unroll
                    for (int q = 0; q < 4; ++q) ok &= (mb[u][q][1] == (unsigned)(j - 1));
                if (__all(ok)) break;
                if (++guard > GUARD_MAX) break;
            }
            // h1_j consumed -> release G1's ring-WAR as early as possible.
            if ((l & 63) == 0)
                __hip_atomic_store(myf2, (unsigned)j, __ATOMIC_RELAXED,
                                   __HIP_MEMORY_SCOPE_AGENT);

            f32x4 acc[4] = {{0,0,0,0},{0,0,0,0},{0,0,0,0},{0,0,0,0}};
            #pragma unroll
            for (int t = 0; t < 8; ++t) {
                frg f;
                f.u[0] = ma[t][0][0]; f.u[1] = ma[t][1][0];
                f.u[2] = ma[t][2][0]; f.u[3] = ma[t][3][0];
                #pragma unroll
                for (int nf = 0; nf < 4; ++nf)
                    acc[nf] = __builtin_amdgcn_mfma_f32_16x16x32_bf16(
                        f.h, wreg[t][nf], acc[nf], 0, 0, 0);
            }
            #pragma unroll
            for (int u = 0; u < 4; ++u) {
                frg f;
                f.u[0] = mb[u][0][0]; f.u[1] = mb[u][1][0];
                f.u[2] = mb[u][2][0]; f.u[3] = mb[u][3][0];
                #pragma unroll
                for (int nf = 0; nf < 4; ++nf)
                    acc[nf] = __builtin_amdgcn_mfma_f32_16x16x32_bf16(
                        f.h, wreg[u + 8][nf], acc[nf], 0, 0, 0);
            }

            #pragma unroll
            for (int nf = 0; nf < 4; ++nf)
                #pragma unroll
                for (int q = 0; q < 4; ++q)
                    red[j & 1][w][kg * 4 + q][nf * 16 + l16] = acc[nf][q];
            __syncthreads();

            if ((l & 63) < 32) {
                f32x4 lo = blo, hi = bhi;
                #pragma unroll
                for (int p = 0; p < 4; ++p) {
                    lo += *reinterpret_cast<const f32x4*>(&red[j & 1][p][r1][c1]);
                    hi += *reinterpret_cast<const f32x4*>(&red[j & 1][p][r1][c1 + 4]);
                }
                float s[8];
                #pragma unroll
                for (int q = 0; q < 4; ++q) { s[q] = ftanh(lo[q]); s[q + 4] = ftanh(hi[q]); }
                char* dp = (char*)(h2m +
                    ((size_t)(sj * 64 + m0 + r1) * 256 + (n0 + c1) / 2));
                const unsigned tg = (unsigned)j;
                #define STU(q, OFF) { pk2 p; p.h[0]=(__bf16)s[2*(q)]; p.h[1]=(__bf16)s[2*(q)+1]; \
                                      u32x2 v; v[0]=p.u; v[1]=tg; st8o<OFF>(dp, v); }
                STU(0, 0) STU(1, 8) STU(2, 16) STU(3, 24)
                #undef STU
                if (j == SS) {
                    float* op = h2out + (m0 + r1) * EE + n0 + c1;
                    #pragma unroll
                    for (int q = 0; q < 8; ++q) op[q] = s[q];
                }
            }
        }
    }
}

// Fallback per-step kernel (round-1 proven path), if cooperative launch fails.
__global__ __launch_bounds__(256) void step_kernel(
    const int* __restrict__ tok32,
    const float* __restrict__ embW,
    const float* __restrict__ b1, const float* __restrict__ b2,
    const __bf16* __restrict__ W1t, const __bf16* __restrict__ W2t,
    const __bf16* __restrict__ h1cur, __bf16* __restrict__ h1next,
    const __bf16* __restrict__ h2cur, __bf16* __restrict__ h2next,
    float* __restrict__ h1f32, float* __restrict__ h2f32,
    int t, int g1, int g2) {
    const int bid = blockIdx.x;
    const bool is1 = bid < 128;
    if (is1 ? (g1 == 0) : (g2 == 0)) return;
    const int rb = is1 ? bid : (bid - 128);
    const int mi = rb & 3;
    const int ni = rb >> 2;
    const int m0 = mi << 4;
    const int n0 = ni << 5;
    const int N = is1 ? HH : EE;
    const int tid = threadIdx.x;
    const int w = tid >> 6;
    const int l = tid & 63;
    const int l16 = l & 15;
    const int kg = l >> 4;

    __shared__ int tok_s[16];
    __shared__ float red[4][16][33];

    if (is1 && tid < 16) tok_s[tid] = tok32[(m0 + tid) * SS + t];
    __syncthreads();

    const __bf16* Wt = is1 ? W1t : W2t;
    f32x4 acc0 = {0.f, 0.f, 0.f, 0.f};
    f32x4 acc1 = {0.f, 0.f, 0.f, 0.f};
    const int row = m0 + l16;
    const int kb = w * 384;

    #pragma unroll 4
    for (int kk = 0; kk < 384; kk += 32) {
        const int k = kb + kk + kg * 8;
        bf16x8 a;
        if (is1) {
            if (k < EE) a = cvt8(embW + (size_t)tok_s[l16] * EE + k);
            else        a = load_bf8(h1cur + row * HH + (k - EE));
        } else {
            if (k < HH) a = load_bf8(h1cur + row * HH + k);
            else        a = load_bf8(h2cur + row * EE + (k - HH));
        }
        bf16x8 bf0 = load_bf8(Wt + (size_t)(n0 + l16) * KK + k);
        bf16x8 bf1 = load_bf8(Wt + (size_t)(n0 + 16 + l16) * KK + k);
        acc0 = __builtin_amdgcn_mfma_f32_16x16x32_bf16(a, bf0, acc0, 0, 0, 0);
        acc1 = __builtin_amdgcn_mfma_f32_16x16x32_bf16(a, bf1, acc1, 0, 0, 0);
    }

    #pragma unroll
    for (int i = 0; i < 4; ++i) {
        red[w][kg * 4 + i][l16]      = acc0[i];
        red[w][kg * 4 + i][16 + l16] = acc1[i];
    }
    __syncthreads();

    const float* bias = is1 ? b1 : b2;
    for (int c = tid; c < 512; c += 256) {
        int m = c >> 5, n = c & 31;
        float s = red[0][m][n] + red[1][m][n] + red[2][m][n] + red[3][m][n];
        s = tanhf(s + bias[n0 + n]);
        int gi = (m0 + m) * N + (n0 + n);
        if (is1) {
            h1next[gi] = (__bf16)s;
            if (h1f32) h1f32[gi] = s;
        } else {
            h2next[gi] = (__bf16)s;
            if (h2f32) h2f32[gi] = s;
        }
    }
}

// Fallback: convert raw final h2 into slot-0 messages for proj.
__global__ void h2tom_kernel(const __bf16* __restrict__ h2raw, u64* __restrict__ h2m) {
    int i = blockIdx.x * 256 + threadIdx.x;
    if (i < 64 * 256) {
        int row = i >> 8, m = i & 255;
        pk2 p;
        p.h[0] = h2raw[row * EE + 2 * m];
        p.h[1] = h2raw[row * EE + 2 * m + 1];
        h2m[i] = ((u64)SS << 32) | (u64)p.u;
    }
}

// out[64, V] = h2 @ emb_W^T + out_b. h2 read from slot-0 messages.
__global__ __launch_bounds__(256) void proj_kernel(
    const u64* __restrict__ h2m,
    const float* __restrict__ embW,
    const float* __restrict__ outb,
    float* __restrict__ out) {
    const int v0 = blockIdx.x << 6;
    const int tid = threadIdx.x;
    const int w = tid >> 6;
    const int l = tid & 63;
    const int l16 = l & 15, kg = l >> 4;
    const int vcol = v0 + w * 16 + l16;
    const int vr = vcol < VV ? vcol : VV - 1;
    f32x4 acc[4] = {{0,0,0,0},{0,0,0,0},{0,0,0,0},{0,0,0,0}};
    #pragma unroll 2
    for (int k0 = 0; k0 < EE; k0 += 32) {
        const int k = k0 + kg * 8;
        bf16x8 bfr = cvt8(embW + (size_t)vr * EE + k);
        #pragma unroll
        for (int mf = 0; mf < 4; ++mf) {
            const u64* hr = h2m + (size_t)(mf * 16 + l16) * 256 + k / 2;
            frg f;
            f.u[0] = (unsigned)hr[0]; f.u[1] = (unsigned)hr[1];
            f.u[2] = (unsigned)hr[2]; f.u[3] = (unsigned)hr[3];
            acc[mf] = __builtin_amdgcn_mfma_f32_16x16x32_bf16(f.h, bfr, acc[mf], 0, 0, 0);
        }
    }
    if (vcol < VV) {
        const float bb = outb[vcol];
        #pragma unroll
        for (int mf = 0; mf < 4; ++mf) {
            #pragma unroll
            for (int i = 0; i < 4; ++i) {
                int b = mf * 16 + kg * 4 + i;
                out[(size_t)b * VV + vcol] = acc[mf][i] + bb;
            }
        }
    }
}

extern "C" void kernel_launch(void* const* d_in, const int* in_sizes, int n_in,
                              void* d_out, int out_size, void* d_ws, size_t ws_size,
                              hipStream_t stream) {
    const void* seq      = d_in[0];
    const float* init_h1 = (const float*)d_in[1];
    const float* init_h2 = (const float*)d_in[2];
    const float* embW    = (const float*)d_in[3];
    const float* W1      = (const float*)d_in[4];
    const float* b1      = (const float*)d_in[5];
    const float* W2      = (const float*)d_in[6];
    const float* b2      = (const float*)d_in[7];
    const float* outb    = (const float*)d_in[8];
    float* out = (float*)d_out;

    char* ws = (char*)d_ws;
    int* tok = (int*)ws;                 ws += (size_t)BB * SS * 4;
    __bf16* W1t = (__bf16*)ws;           ws += (size_t)HH * KK * 2;
    __bf16* W2t = (__bf16*)ws;           ws += (size_t)EE * KK * 2;
    u64* h1m = (u64*)ws;                 ws += (size_t)8 * 64 * 512 * 8;
    u64* h2m = (u64*)ws;                 ws += (size_t)8 * 64 * 256 * 8;
    unsigned* bar = (unsigned*)ws;       ws += (size_t)4 * 32 * PADU * 4;
    __bf16* h1p = (__bf16*)ws;           ws += (size_t)2 * BB * HH * 2;  // fallback
    __bf16* h2p = (__bf16*)ws;           ws += (size_t)2 * BB * EE * 2;  // fallback

    hipLaunchKernelGGL(tokens_kernel, dim3(128), dim3(256), 0, stream, seq, tok, bar);
    hipLaunchKernelGGL(transpose_kernel, dim3((KK / 32) * (HH / 32)), dim3(256), 0, stream,
                       W1, W1t, KK, HH);
    hipLaunchKernelGGL(transpose_kernel, dim3((KK / 32) * (EE / 32)), dim3(256), 0, stream,
                       W2, W2t, KK, EE);
    hipLaunchKernelGGL(msgclear_kernel, dim3(1344), dim3(256), 0, stream, h1m, h2m);
    hipLaunchKernelGGL(init_kernel, dim3(192), dim3(256), 0, stream,
                       init_h1, init_h2, h1m, h2m, h1p, h2p);

    float* h1out = out + (size_t)BB * VV;
    float* h2out = h1out + (size_t)BB * HH;

    const int* tok_c = tok;
    const __bf16* W1t_c = W1t;
    const __bf16* W2t_c = W2t;
    void* args[] = {
        (void*)&tok_c, (void*)&embW, (void*)&b1, (void*)&b2,
        (void*)&W1t_c, (void*)&W2t_c,
        (void*)&h1m, (void*)&h2m,
        (void*)&h1out, (void*)&h2out, (void*)&bar
    };
    hipError_t err = hipLaunchCooperativeKernel((void*)rnn_persist5, dim3(NWG), dim3(256),
                                                args, 0, stream);
    if (err != hipSuccess) {
        // Deterministic fallback: proven per-step path (round 1).
        __bf16* h1bf[2] = {h1p, h1p + (size_t)BB * HH};
        __bf16* h2bf[2] = {h2p, h2p + (size_t)BB * EE};
        for (int t = 0; t <= SS; ++t) {
            int g1 = (t < SS) ? 1 : 0;
            int g2 = (t >= 1) ? 1 : 0;
            const __bf16* h1cur = h1bf[t & 1];
            __bf16* h1next      = h1bf[(t + 1) & 1];
            const __bf16* h2cur = h2bf[(t + 1) & 1];
            __bf16* h2next      = h2bf[t & 1];
            float* h1f = (t == SS - 1) ? h1out : nullptr;
            float* h2f = (t == SS) ? h2out : nullptr;
            hipLaunchKernelGGL(step_kernel, dim3(192), dim3(256), 0, stream,
                               tok, embW, b1, b2, W1t, W2t,
                               h1cur, h1next, h2cur, h2next, h1f, h2f, t, g1, g2);
        }
        hipLaunchKernelGGL(h2tom_kernel, dim3(64), dim3(256), 0, stream, h2bf[0], h2m);
    }

    // h2_512 lives in message slot 0 (512 % 8 == 0) on both paths.
    hipLaunchKernelGGL(proj_kernel, dim3((VV + 63) / 64), dim3(256), 0, stream,
                       h2m, embW, outb, out);
}

// Round 11
// 2067.836 us; speedup vs baseline: 1.8372x; 1.8372x over previous
//
#include <hip/hip_runtime.h>
#include <hip/hip_bf16.h>

#define BB 64
#define EE 512
#define HH 1024
#define KK 1536
#define VV 50257
#define SS 512

#define NWG1 64    // G1 blocks: mi=bid&3 (16 rows), ni=bid>>2 (16 x 64-col tiles)
#define NWG2 32    // G2 blocks: mi=rb&3,  ni=rb>>2 (8 x 64-col tiles)
#define NWG (NWG1 + NWG2)
#define RING 64    // deep ring: G2 gets 63 steps of slack, WAR check ~amortized out
#define PADU 32    // unsigned per flag slot = 128 B line

typedef __bf16 bf16x8 __attribute__((ext_vector_type(8)));
typedef float f32x4 __attribute__((ext_vector_type(4)));

__device__ __forceinline__ bf16x8 load_bf8(const __bf16* p) {
    return *reinterpret_cast<const bf16x8*>(p);
}

__device__ __forceinline__ bf16x8 cvt8(const float* p) {
    f32x4 a = *reinterpret_cast<const f32x4*>(p);
    f32x4 b = *reinterpret_cast<const f32x4*>(p + 4);
    bf16x8 r;
    r[0] = (__bf16)a[0]; r[1] = (__bf16)a[1]; r[2] = (__bf16)a[2]; r[3] = (__bf16)a[3];
    r[4] = (__bf16)b[0]; r[5] = (__bf16)b[1]; r[6] = (__bf16)b[2]; r[7] = (__bf16)b[3];
    return r;
}

// 16B coherent load/store (round-7/8-proven): sc0 sc1 -> device coherence point.
__device__ __forceinline__ void st16c(void* p, f32x4 v) {
    asm volatile("global_store_dwordx4 %0, %1, off sc0 sc1" :: "v"(p), "v"(v) : "memory");
}
__device__ __forceinline__ f32x4 ld16c(const void* p) {
    f32x4 r;
    asm volatile("global_load_dwordx4 %0, %1, off sc0 sc1" : "=v"(r) : "v"(p) : "memory");
    return r;
}
union cvu { f32x4 f; bf16x8 h8; __bf16 h[8]; };

// Block-level wait: wave 0 polls nslots block-flag lines, barrier releases.
// (vs round 8's all-wave polling: 16x less flag-line read pressure, so
// producer flag STORES to those lines stop queueing behind poll reads.)
__device__ __forceinline__ void block_wait(const unsigned* slots, int nslots,
                                           unsigned target) {
    if (threadIdx.x < 64) {
        const int l = threadIdx.x;
        const int idx = l < nslots ? l : 0;
        for (;;) {
            unsigned v = __hip_atomic_load(&slots[idx * PADU], __ATOMIC_RELAXED,
                                           __HIP_MEMORY_SCOPE_AGENT);
            if (l >= nslots) v = target;
            if (__all((int)(v >= target))) break;
            __builtin_amdgcn_s_sleep(1);
        }
    }
    __syncthreads();
    asm volatile("" ::: "memory");
}

// Wave-parallel min over nslots block-flag slots (broadcast to all lanes).
__device__ __forceinline__ unsigned minpoll(const unsigned* slots, int nslots) {
    const int l = threadIdx.x & 63;
    unsigned v = 0xFFFFFFFFu;
    if (l < nslots)
        v = __hip_atomic_load(&slots[l * PADU], __ATOMIC_RELAXED,
                              __HIP_MEMORY_SCOPE_AGENT);
    #pragma unroll
    for (int o = 32; o; o >>= 1) {
        unsigned u = (unsigned)__shfl_xor((int)v, o, 64);
        v = u < v ? u : v;
    }
    return v;
}

// Block-level publish: every wave drains its own coherent stores, barrier,
// then one lane posts the block flag.
__device__ __forceinline__ void bsignal(unsigned* slot, unsigned val) {
    asm volatile("s_waitcnt vmcnt(0)" ::: "memory");
    __syncthreads();
    if (threadIdx.x == 0)
        __hip_atomic_store(slot, val, __ATOMIC_RELAXED, __HIP_MEMORY_SCOPE_AGENT);
}

// Fast tanh via v_exp; rel err ~1e-6 << bf16 storage quantization.
__device__ __forceinline__ float ftanh(float x) {
    float ax = fabsf(x);
    float e = __expf(-2.0f * ax);
    float r = (1.0f - e) / (1.0f + e);
    return x < 0.0f ? -r : r;
}

// Decode tokens to int32 (auto-detect int64 vs int32) + zero the flag slots.
__global__ void tokens_kernel(const void* __restrict__ seq, int* __restrict__ tok,
                              unsigned* __restrict__ bar) {
    int z = blockIdx.x * 256 + threadIdx.x;
    if (z < 4 * 32 * PADU)
        __hip_atomic_store(&bar[z], 0u, __ATOMIC_RELAXED, __HIP_MEMORY_SCOPE_AGENT);
    const unsigned* u = (const unsigned*)seq;
    bool is64 = true;
    #pragma unroll 1
    for (int i = 0; i < 64; ++i) {
        if (u[2 * i + 1] != 0u) { is64 = false; break; }
    }
    int i = blockIdx.x * 256 + threadIdx.x;
    if (i < BB * SS) tok[i] = is64 ? (int)u[2 * i] : (int)u[i];
}

// fp32 [R][C] row-major -> bf16 [C][R]
__global__ __launch_bounds__(256) void transpose_kernel(
    const float* __restrict__ in, __bf16* __restrict__ out, int R, int C) {
    __shared__ float t[32][33];
    int bc = C >> 5;
    int br = blockIdx.x / bc;
    int bco = blockIdx.x % bc;
    int R0 = br << 5, C0 = bco << 5;
    int c = threadIdx.x & 31, r0 = threadIdx.x >> 5;
    #pragma unroll
    for (int i = 0; i < 4; ++i) {
        int r = r0 + i * 8;
        t[r][c] = in[(size_t)(R0 + r) * C + C0 + c];
    }
    __syncthreads();
    #pragma unroll
    for (int i = 0; i < 4; ++i) {
        int r = r0 + i * 8;
        out[(size_t)(C0 + r) * R + R0 + c] = (__bf16)t[c][r];
    }
}

__global__ void init_kernel(const float* __restrict__ h1, const float* __restrict__ h2,
                            __bf16* __restrict__ h1bf, __bf16* __restrict__ h2bf) {
    int i = blockIdx.x * 256 + threadIdx.x;
    if (i < BB * HH) h1bf[i] = (__bf16)h1[i];
    if (i < BB * EE) h2bf[i] = (__bf16)h2[i];
}

// Persistent DECOUPLED-chain recurrence (round-8 structure), block flags +
// deep rings.
// G1@i: emb MFMAs (pre-wait) -> [rare WAR check f2min>=i-63] -> wait f1>=i ->
//   h1_i loads -> 32 MFMA/wave -> LDS reduce -> tanh -> store h1_{i+1} ->
//   block signal f1=i+1.
// G2@j (trails, 63 steps of slack): wait f1>=j -> h1_j loads -> wait f2>=j-1
//   -> h2_{j-1} loads -> 48 MFMA/wave -> reduce -> store h2_j -> f2=j.
// Ring WAR (depth 64): G1 writing slot (i+1)&63 destroys h1_{i-63}; G2
// consumed it iff f2min >= i-63 (checked, cached). G2 peers lockstep +-1 via
// the f2 wait -> h2 ring trivially safe. All exchange via proven sc0sc1 ops.
__global__ __launch_bounds__(256, 1) void rnn_persist6(
    const int* __restrict__ tok32, const float* __restrict__ embW,
    const float* __restrict__ b1, const float* __restrict__ b2,
    const __bf16* __restrict__ W1t, const __bf16* __restrict__ W2t,
    __bf16* __restrict__ h1r, __bf16* __restrict__ h2r,
    float* __restrict__ h1out, float* __restrict__ h2out,
    unsigned* __restrict__ bar) {
    const int bid = blockIdx.x;
    const bool g1 = bid < NWG1;
    const int rb = g1 ? bid : bid - NWG1;
    const int mi = rb & 3;
    const int ni = rb >> 2;          // 0..15 (G1) / 0..7 (G2)
    const int m0 = mi << 4;
    const int n0 = ni << 6;
    const int tid = threadIdx.x;
    const int w = tid >> 6;
    const int l = tid & 63;
    const int l16 = l & 15;
    const int kg = l >> 4;
    unsigned* f1s = bar + mi * (32 * PADU);   // 16 block flags
    unsigned* f2s = f1s + 16 * PADU;          // 8 block flags
    unsigned* myf = g1 ? &f1s[ni * PADU] : &f2s[ni * PADU];

    __shared__ int tok_s[SS][16];
    __shared__ float red[2][4][16][68];   // double-buffered cross-wave reduce

    if (g1) {
        for (int idx = tid; idx < SS * 16; idx += 256) {
            int t = idx >> 4, r = idx & 15;
            tok_s[t][r] = tok32[(m0 + r) * SS + t];
        }
    }

    // Register-resident weights: wave w holds K-slices {w+4t, t=0..11}.
    const __bf16* Wt = g1 ? W1t : W2t;
    bf16x8 wreg[12][4];
    #pragma unroll
    for (int t = 0; t < 12; ++t) {
        const int kb = 32 * (w + 4 * t) + kg * 8;
        #pragma unroll
        for (int nf = 0; nf < 4; ++nf)
            wreg[t][nf] = load_bf8(Wt + (size_t)(n0 + nf * 16 + l16) * KK + kb);
    }
    {   // Pin in the register file (round-3 lesson: else re-fetched per step).
        f32x4* p1 = reinterpret_cast<f32x4*>(&wreg[0][0]);
        #pragma unroll
        for (int q = 0; q < 48; ++q) asm volatile("" : "+v"(p1[q]));
    }

    // Epilogue mapping (lanes<32): row = 4w + (l>>3), cols c1 = (l&7)*8.
    const int r1 = 4 * w + ((l & 31) >> 3);
    const int c1 = (l & 7) * 8;
    const float* bias = g1 ? b1 : b2;
    const f32x4 blo = *reinterpret_cast<const f32x4*>(bias + n0 + c1);
    const f32x4 bhi = *reinterpret_cast<const f32x4*>(bias + n0 + c1 + 4);

    unsigned f2c = 0;  // G1's cached min of f2 flags (ring-WAR)

    __syncthreads();

    if (g1) {
        // ---------------- h1 chain (the critical path) ----------------
        for (int i = 0; i < SS; ++i) {
            const __bf16* h1i = h1r + (size_t)(i & (RING - 1)) * BB * HH;
            __bf16*       h1n = h1r + (size_t)((i + 1) & (RING - 1)) * BB * HH;

            // Pre-wait: embedding-part MFMAs (cached path).
            f32x4 acc[4] = {{0,0,0,0},{0,0,0,0},{0,0,0,0},{0,0,0,0}};
            const float* er = embW + (size_t)tok_s[i][l16] * EE;
            #pragma unroll
            for (int t = 0; t < 4; ++t) {
                bf16x8 ae = cvt8(er + 32 * (w + 4 * t) + kg * 8);
                #pragma unroll
                for (int nf = 0; nf < 4; ++nf)
                    acc[nf] = __builtin_amdgcn_mfma_f32_16x16x32_bf16(
                        ae, wreg[t][nf], acc[nf], 0, 0, 0);
            }
            __builtin_amdgcn_sched_barrier(0);

            // Rare ring-WAR check: slot (i+1)&63 holds h1_{i-63}.
            if (i >= RING - 1 && (int)f2c < i - (RING - 1)) {
                do { f2c = minpoll(f2s, 8); } while ((int)f2c < i - (RING - 1));
            }

            if (i) block_wait(f1s, 16, (unsigned)i);   // the ONE hop per step

            const __bf16* h1row = h1i + (m0 + l16) * HH;
            bf16x8 ah[8];
            #pragma unroll
            for (int u = 0; u < 8; ++u) {
                cvu t_; t_.f = ld16c(h1row + 32 * (w + 4 * u) + kg * 8);
                ah[u] = t_.h8;
            }
            asm volatile("s_waitcnt vmcnt(0)" ::: "memory");
            __builtin_amdgcn_sched_barrier(0);

            #pragma unroll
            for (int u = 0; u < 8; ++u)
                #pragma unroll
                for (int nf = 0; nf < 4; ++nf)
                    acc[nf] = __builtin_amdgcn_mfma_f32_16x16x32_bf16(
                        ah[u], wreg[u + 4][nf], acc[nf], 0, 0, 0);

            // D layout: col = lane&15, row = (lane>>4)*4 + reg.
            #pragma unroll
            for (int nf = 0; nf < 4; ++nf)
                #pragma unroll
                for (int q = 0; q < 4; ++q)
                    red[i & 1][w][kg * 4 + q][nf * 16 + l16] = acc[nf][q];
            __syncthreads();

            if ((l & 63) < 32) {
                f32x4 lo = blo, hi = bhi;
                #pragma unroll
                for (int p = 0; p < 4; ++p) {
                    lo += *reinterpret_cast<const f32x4*>(&red[i & 1][p][r1][c1]);
                    hi += *reinterpret_cast<const f32x4*>(&red[i & 1][p][r1][c1 + 4]);
                }
                cvu o;
                #pragma unroll
                for (int j = 0; j < 4; ++j) {
                    o.h[j]     = (__bf16)ftanh(lo[j]);
                    o.h[j + 4] = (__bf16)ftanh(hi[j]);
                }
                st16c(h1n + (m0 + r1) * HH + n0 + c1, o.f);
                if (i == SS - 1) {
                    float* op = h1out + (m0 + r1) * HH + n0 + c1;
                    #pragma unroll
                    for (int j = 0; j < 8; ++j)
                        op[j] = __bfloat162float(((__hip_bfloat16*)&o.h[j])[0]);
                }
            }
            bsignal(myf, (unsigned)(i + 1));
        }
    } else {
        // ---------------- h2 chain (63 steps of slack) ----------------
        for (int j = 1; j <= SS; ++j) {
            const __bf16* h1j = h1r + (size_t)(j & (RING - 1)) * BB * HH;
            const __bf16* h2p = h2r + (size_t)((j - 1) & (RING - 1)) * BB * EE;
            __bf16*       h2n = h2r + (size_t)(j & (RING - 1)) * BB * EE;

            block_wait(f1s, 16, (unsigned)j);          // instant when trailing
            const __bf16* h1row = h1j + (m0 + l16) * HH;
            bf16x8 ah[8];
            #pragma unroll
            for (int t = 0; t < 8; ++t) {
                cvu t_; t_.f = ld16c(h1row + 32 * (w + 4 * t) + kg * 8);
                ah[t] = t_.h8;
            }
            if (j >= 2) block_wait(f2s, 8, (unsigned)(j - 1));  // own hop
            const __bf16* h2row = h2p + (m0 + l16) * EE;
            bf16x8 a2[4];
            #pragma unroll
            for (int u = 0; u < 4; ++u) {
                cvu t_; t_.f = ld16c(h2row + 32 * (w + 4 * u) + kg * 8);
                a2[u] = t_.h8;
            }
            asm volatile("s_waitcnt vmcnt(0)" ::: "memory");
            __builtin_amdgcn_sched_barrier(0);

            f32x4 acc[4] = {{0,0,0,0},{0,0,0,0},{0,0,0,0},{0,0,0,0}};
            #pragma unroll
            for (int t = 0; t < 8; ++t)
                #pragma unroll
                for (int nf = 0; nf < 4; ++nf)
                    acc[nf] = __builtin_amdgcn_mfma_f32_16x16x32_bf16(
                        ah[t], wreg[t][nf], acc[nf], 0, 0, 0);
            #pragma unroll
            for (int u = 0; u < 4; ++u)
                #pragma unroll
                for (int nf = 0; nf < 4; ++nf)
                    acc[nf] = __builtin_amdgcn_mfma_f32_16x16x32_bf16(
                        a2[u], wreg[u + 8][nf], acc[nf], 0, 0, 0);

            #pragma unroll
            for (int nf = 0; nf < 4; ++nf)
                #pragma unroll
                for (int q = 0; q < 4; ++q)
                    red[j & 1][w][kg * 4 + q][nf * 16 + l16] = acc[nf][q];
            __syncthreads();

            if ((l & 63) < 32) {
                f32x4 lo = blo, hi = bhi;
                #pragma unroll
                for (int p = 0; p < 4; ++p) {
                    lo += *reinterpret_cast<const f32x4*>(&red[j & 1][p][r1][c1]);
                    hi += *reinterpret_cast<const f32x4*>(&red[j & 1][p][r1][c1 + 4]);
                }
                cvu o;
                #pragma unroll
                for (int q = 0; q < 4; ++q) {
                    o.h[q]     = (__bf16)ftanh(lo[q]);
                    o.h[q + 4] = (__bf16)ftanh(hi[q]);
                }
                st16c(h2n + (m0 + r1) * EE + n0 + c1, o.f);
                if (j == SS) {
                    float* op = h2out + (m0 + r1) * EE + n0 + c1;
                    #pragma unroll
                    for (int q = 0; q < 8; ++q)
                        op[q] = __bfloat162float(((__hip_bfloat16*)&o.h[q])[0]);
                }
            }
            bsignal(myf, (unsigned)j);
        }
    }
}

// Fallback per-step kernel (round-1 proven path), if cooperative launch fails.
__global__ __launch_bounds__(256) void step_kernel(
    const int* __restrict__ tok32,
    const float* __restrict__ embW,
    const float* __restrict__ b1, const float* __restrict__ b2,
    const __bf16* __restrict__ W1t, const __bf16* __restrict__ W2t,
    const __bf16* __restrict__ h1cur, __bf16* __restrict__ h1next,
    const __bf16* __restrict__ h2cur, __bf16* __restrict__ h2next,
    float* __restrict__ h1f32, float* __restrict__ h2f32,
    int t, int g1, int g2) {
    const int bid = blockIdx.x;
    const bool is1 = bid < 128;
    if (is1 ? (g1 == 0) : (g2 == 0)) return;
    const int rb = is1 ? bid : (bid - 128);
    const int mi = rb & 3;
    const int ni = rb >> 2;
    const int m0 = mi << 4;
    const int n0 = ni << 5;
    const int N = is1 ? HH : EE;
    const int tid = threadIdx.x;
    const int w = tid >> 6;
    const int l = tid & 63;
    const int l16 = l & 15;
    const int kg = l >> 4;

    __shared__ int tok_s[16];
    __shared__ float red[4][16][33];

    if (is1 && tid < 16) tok_s[tid] = tok32[(m0 + tid) * SS + t];
    __syncthreads();

    const __bf16* Wt = is1 ? W1t : W2t;
    f32x4 acc0 = {0.f, 0.f, 0.f, 0.f};
    f32x4 acc1 = {0.f, 0.f, 0.f, 0.f};
    const int row = m0 + l16;
    const int kb = w * 384;

    #pragma unroll 4
    for (int kk = 0; kk < 384; kk += 32) {
        const int k = kb + kk + kg * 8;
        bf16x8 a;
        if (is1) {
            if (k < EE) a = cvt8(embW + (size_t)tok_s[l16] * EE + k);
            else        a = load_bf8(h1cur + row * HH + (k - EE));
        } else {
            if (k < HH) a = load_bf8(h1cur + row * HH + k);
            else        a = load_bf8(h2cur + row * EE + (k - HH));
        }
        bf16x8 bf0 = load_bf8(Wt + (size_t)(n0 + l16) * KK + k);
        bf16x8 bf1 = load_bf8(Wt + (size_t)(n0 + 16 + l16) * KK + k);
        acc0 = __builtin_amdgcn_mfma_f32_16x16x32_bf16(a, bf0, acc0, 0, 0, 0);
        acc1 = __builtin_amdgcn_mfma_f32_16x16x32_bf16(a, bf1, acc1, 0, 0, 0);
    }

    #pragma unroll
    for (int i = 0; i < 4; ++i) {
        red[w][kg * 4 + i][l16]      = acc0[i];
        red[w][kg * 4 + i][16 + l16] = acc1[i];
    }
    __syncthreads();

    const float* bias = is1 ? b1 : b2;
    for (int c = tid; c < 512; c += 256) {
        int m = c >> 5, n = c & 31;
        float s = red[0][m][n] + red[1][m][n] + red[2][m][n] + red[3][m][n];
        s = tanhf(s + bias[n0 + n]);
        int gi = (m0 + m) * N + (n0 + n);
        if (is1) {
            h1next[gi] = (__bf16)s;
            if (h1f32) h1f32[gi] = s;
        } else {
            h2next[gi] = (__bf16)s;
            if (h2f32) h2f32[gi] = s;
        }
    }
}

// out[64, V] = h2 @ emb_W^T + out_b.
__global__ __launch_bounds__(256) void proj_kernel(
    const __bf16* __restrict__ h2bf,
    const float* __restrict__ embW,
    const float* __restrict__ outb,
    float* __restrict__ out) {
    const int v0 = blockIdx.x << 6;
    const int tid = threadIdx.x;
    const int w = tid >> 6;
    const int l = tid & 63;
    const int l16 = l & 15, kg = l >> 4;
    const int vcol = v0 + w * 16 + l16;
    const int vr = vcol < VV ? vcol : VV - 1;
    f32x4 acc[4] = {{0,0,0,0},{0,0,0,0},{0,0,0,0},{0,0,0,0}};
    #pragma unroll 2
    for (int k0 = 0; k0 < EE; k0 += 32) {
        const int k = k0 + kg * 8;
        bf16x8 bfr = cvt8(embW + (size_t)vr * EE + k);
        #pragma unroll
        for (int mf = 0; mf < 4; ++mf) {
            bf16x8 a = load_bf8(h2bf + (mf * 16 + l16) * EE + k);
            acc[mf] = __builtin_amdgcn_mfma_f32_16x16x32_bf16(a, bfr, acc[mf], 0, 0, 0);
        }
    }
    if (vcol < VV) {
        const float bb = outb[vcol];
        #pragma unroll
        for (int mf = 0; mf < 4; ++mf) {
            #pragma unroll
            for (int i = 0; i < 4; ++i) {
                int b = mf * 16 + kg * 4 + i;
                out[(size_t)b * VV + vcol] = acc[mf][i] + bb;
            }
        }
    }
}

extern "C" void kernel_launch(void* const* d_in, const int* in_sizes, int n_in,
                              void* d_out, int out_size, void* d_ws, size_t ws_size,
                              hipStream_t stream) {
    const void* seq      = d_in[0];
    const float* init_h1 = (const float*)d_in[1];
    const float* init_h2 = (const float*)d_in[2];
    const float* embW    = (const float*)d_in[3];
    const float* W1      = (const float*)d_in[4];
    const float* b1      = (const float*)d_in[5];
    const float* W2      = (const float*)d_in[6];
    const float* b2      = (const float*)d_in[7];
    const float* outb    = (const float*)d_in[8];
    float* out = (float*)d_out;

    char* ws = (char*)d_ws;
    int* tok = (int*)ws;                 ws += (size_t)BB * SS * 4;
    __bf16* W1t = (__bf16*)ws;           ws += (size_t)HH * KK * 2;
    __bf16* W2t = (__bf16*)ws;           ws += (size_t)EE * KK * 2;
    __bf16* h1r = (__bf16*)ws;           ws += (size_t)RING * BB * HH * 2;
    __bf16* h2r = (__bf16*)ws;           ws += (size_t)RING * BB * EE * 2;
    unsigned* bar = (unsigned*)ws;       ws += (size_t)4 * 32 * PADU * 4;

    hipLaunchKernelGGL(tokens_kernel, dim3(128), dim3(256), 0, stream, seq, tok, bar);
    hipLaunchKernelGGL(transpose_kernel, dim3((KK / 32) * (HH / 32)), dim3(256), 0, stream,
                       W1, W1t, KK, HH);
    hipLaunchKernelGGL(transpose_kernel, dim3((KK / 32) * (EE / 32)), dim3(256), 0, stream,
                       W2, W2t, KK, EE);
    // init states into ring slot 0
    hipLaunchKernelGGL(init_kernel, dim3(256), dim3(256), 0, stream,
                       init_h1, init_h2, h1r, h2r);

    float* h1out = out + (size_t)BB * VV;
    float* h2out = h1out + (size_t)BB * HH;

    const int* tok_c = tok;
    const __bf16* W1t_c = W1t;
    const __bf16* W2t_c = W2t;
    void* args[] = {
        (void*)&tok_c, (void*)&embW, (void*)&b1, (void*)&b2,
        (void*)&W1t_c, (void*)&W2t_c,
        (void*)&h1r, (void*)&h2r,
        (void*)&h1out, (void*)&h2out, (void*)&bar
    };
    hipError_t err = hipLaunchCooperativeKernel((void*)rnn_persist6, dim3(NWG), dim3(256),
                                                args, 0, stream);
    if (err != hipSuccess) {
        // Deterministic fallback: proven per-step path (round 1), ring slots 0/1.
        __bf16* h1bf[2] = {h1r, h1r + (size_t)BB * HH};
        __bf16* h2bf[2] = {h2r, h2r + (size_t)BB * EE};
        for (int t = 0; t <= SS; ++t) {
            int g1 = (t < SS) ? 1 : 0;
            int g2 = (t >= 1) ? 1 : 0;
            const __bf16* h1cur = h1bf[t & 1];
            __bf16* h1next      = h1bf[(t + 1) & 1];
            const __bf16* h2cur = h2bf[(t + 1) & 1];
            __bf16* h2next      = h2bf[t & 1];
            float* h1f = (t == SS - 1) ? h1out : nullptr;
            float* h2f = (t == SS) ? h2out : nullptr;
            hipLaunchKernelGGL(step_kernel, dim3(192), dim3(256), 0, stream,
                               tok, embW, b1, b2, W1t, W2t,
                               h1cur, h1next, h2cur, h2next, h1f, h2f, t, g1, g2);
        }
    }

    // h2_512 lives in ring slot 0 (512 % 64 == 0) on both paths.
    hipLaunchKernelGGL(proj_kernel, dim3((VV + 63) / 64), dim3(256), 0, stream,
                       h2r, embW, outb, out);
}